// Round 1
// baseline (204.270 us; speedup 1.0000x reference)
//
#include <hip/hip_runtime.h>
#include <hip/hip_bf16.h>

typedef __attribute__((ext_vector_type(8))) short bf16x8;
typedef __attribute__((ext_vector_type(4))) float f32x4;
typedef __attribute__((ext_vector_type(4))) short short4v;

#define D128 128
#define TILE_M 128
#define LDA 136  // 128 + 8 bf16 pad: fragment reads land 2-way bank aliased (free)

__device__ __forceinline__ short f2bf(float f) {
    union { float f; unsigned u; } v; v.f = f;
    unsigned r = (v.u + 0x7FFFu + ((v.u >> 16) & 1u)) >> 16;  // RNE
    return (short)r;
}

// Transpose W (3*128 x 128, fp32 row-major) -> WT[c][n][k] bf16 in workspace.
// Grid: 48 blocks (c = bid>>4, n0 = (bid&15)*8), 256 threads.
__global__ __launch_bounds__(256) void wt_kernel(const float* __restrict__ W,
                                                 short* __restrict__ WT) {
    const int c  = blockIdx.x >> 4;
    const int n0 = (blockIdx.x & 15) * 8;
    const int tid = threadIdx.x;
#pragma unroll
    for (int i = 0; i < 4; ++i) {
        int li = i * 256 + tid;          // 0..1023
        int nn = li >> 7;                // 0..7
        int k  = li & 127;               // 0..127
        float v = W[(size_t)(c * 128 + k) * D128 + (n0 + nn)];
        WT[(size_t)c * (D128 * D128) + (size_t)(n0 + nn) * D128 + k] = f2bf(v);
    }
}

// Fused gather-GEMM: out[r] = bf16mfma( [x[src[r]] | x[dst[r]] | e[r]] @ W )
// Tile: 128 rows x 128 cols per block, 4 waves (each wave: 32 rows x 128 cols).
__global__ __launch_bounds__(256, 2) void fused_kernel(
        const float* __restrict__ x,
        const float* __restrict__ e,
        const short* __restrict__ WT,
        const int*  __restrict__ src_idx,
        const int*  __restrict__ dst_idx,
        float* __restrict__ out)
{
    __shared__ short As[TILE_M * LDA];   // 34816 B
    __shared__ short Ws[D128 * LDA];     // 34816 B
    __shared__ int   sidx[TILE_M];
    __shared__ int   didx[TILE_M];

    const int tid = threadIdx.x;
    const int r0  = blockIdx.x * TILE_M;

    if (tid < TILE_M) {
        sidx[tid] = src_idx[r0 + tid];
        didx[tid] = dst_idx[r0 + tid];
    }
    __syncthreads();

    const int wave = tid >> 6;
    const int lane = tid & 63;
    const int lrow = lane & 15;
    const int lhi  = lane >> 4;   // 0..3

    f32x4 acc[2][8];
#pragma unroll
    for (int i = 0; i < 2; ++i)
#pragma unroll
        for (int n = 0; n < 8; ++n)
            acc[i][n] = (f32x4){0.f, 0.f, 0.f, 0.f};

    for (int c = 0; c < 3; ++c) {
        // ---- stage A: 128 gathered rows, fp32 -> bf16 into LDS ----
        const float* base = (c == 2) ? e : x;
        const int*   idxs = (c == 0) ? sidx : didx;
#pragma unroll
        for (int i = 0; i < 16; ++i) {
            int li  = i * 256 + tid;     // 0..4095
            int row = li >> 5;           // 0..127
            int c4  = li & 31;           // float4 index within row
            size_t grow = (c == 2) ? (size_t)(r0 + row) : (size_t)idxs[row];
            const float4 v = reinterpret_cast<const float4*>(base + grow * D128)[c4];
            short4v b;
            b.x = f2bf(v.x); b.y = f2bf(v.y); b.z = f2bf(v.z); b.w = f2bf(v.w);
            *reinterpret_cast<short4v*>(&As[row * LDA + c4 * 4]) = b;
        }
        // ---- stage Wt chunk: coalesced bf16x8 copies ----
        const short* Wc = WT + (size_t)c * (D128 * D128);
#pragma unroll
        for (int i = 0; i < 8; ++i) {
            int li = i * 256 + tid;      // 0..2047 (16B units)
            int n  = li >> 4;            // 0..127
            int k8 = li & 15;            // 0..15
            bf16x8 w = reinterpret_cast<const bf16x8*>(Wc)[li];
            *reinterpret_cast<bf16x8*>(&Ws[n * LDA + k8 * 8]) = w;
        }
        __syncthreads();

        // ---- MFMA: K=128 in 4 steps of 32 ----
        const int arow0 = (wave * 32 + lrow) * LDA + lhi * 8;
        const int arow1 = arow0 + 16 * LDA;
#pragma unroll
        for (int ks = 0; ks < 4; ++ks) {
            bf16x8 a0 = *reinterpret_cast<const bf16x8*>(&As[arow0 + ks * 32]);
            bf16x8 a1 = *reinterpret_cast<const bf16x8*>(&As[arow1 + ks * 32]);
#pragma unroll
            for (int n = 0; n < 8; ++n) {
                bf16x8 b = *reinterpret_cast<const bf16x8*>(
                    &Ws[(n * 16 + lrow) * LDA + ks * 32 + lhi * 8]);
                acc[0][n] = __builtin_amdgcn_mfma_f32_16x16x32_bf16(a0, b, acc[0][n], 0, 0, 0);
                acc[1][n] = __builtin_amdgcn_mfma_f32_16x16x32_bf16(a1, b, acc[1][n], 0, 0, 0);
            }
        }
        __syncthreads();
    }

    // ---- epilogue: C/D layout col=lane&15, row=(lane>>4)*4+reg ----
#pragma unroll
    for (int rg = 0; rg < 2; ++rg) {
#pragma unroll
        for (int n = 0; n < 8; ++n) {
#pragma unroll
            for (int j = 0; j < 4; ++j) {
                int row = r0 + wave * 32 + rg * 16 + lhi * 4 + j;
                int col = n * 16 + lrow;
                out[(size_t)row * D128 + col] = acc[rg][n][j];
            }
        }
    }
}

extern "C" void kernel_launch(void* const* d_in, const int* in_sizes, int n_in,
                              void* d_out, int out_size, void* d_ws, size_t ws_size,
                              hipStream_t stream) {
    const float* x = (const float*)d_in[0];
    const float* e = (const float*)d_in[1];
    const float* W = (const float*)d_in[2];
    const int* src = (const int*)d_in[3];
    const int* dst = (const int*)d_in[4];
    float* out = (float*)d_out;
    short* WT  = (short*)d_ws;   // 3*128*128 bf16 = 96 KiB

    const int E = in_sizes[3];               // 400000
    const int blocks = E / TILE_M;           // 3125 (exact)

    wt_kernel<<<48, 256, 0, stream>>>(W, WT);
    fused_kernel<<<blocks, 256, 0, stream>>>(x, e, WT, src, dst, out);
}

// Round 2
// 196.712 us; speedup vs baseline: 1.0384x; 1.0384x over previous
//
#include <hip/hip_runtime.h>
#include <hip/hip_bf16.h>

typedef __attribute__((ext_vector_type(8))) short bf16x8;
typedef __attribute__((ext_vector_type(4))) float f32x4;

#define D128 128
#define TILE_M 128
#define LDW 136  // 128 + 8 bf16 pad for Ws fragment reads

// Manual RNE f32->bf16 (used in cold transpose kernel)
__device__ __forceinline__ short f2bf(float f) {
    union { float f; unsigned u; } v; v.f = f;
    unsigned r = (v.u + 0x7FFFu + ((v.u >> 16) & 1u)) >> 16;
    return (short)r;
}

// Hot-path f32->bf16 via HIP intrinsic (RNE); compiler emits v_cvt_pk_bf16_f32 pairs.
__device__ __forceinline__ short f2bf_h(float f) {
    __hip_bfloat16 h = __float2bfloat16(f);
    short s;
    __builtin_memcpy(&s, &h, sizeof(short));
    return s;
}

__device__ __forceinline__ bf16x8 pack8(float4 a, float4 b) {
    bf16x8 r;
    r[0] = f2bf_h(a.x); r[1] = f2bf_h(a.y); r[2] = f2bf_h(a.z); r[3] = f2bf_h(a.w);
    r[4] = f2bf_h(b.x); r[5] = f2bf_h(b.y); r[6] = f2bf_h(b.z); r[7] = f2bf_h(b.w);
    return r;
}

// Transpose W (3*128 x 128, fp32 row-major) -> WT[c][n][k] bf16 in workspace.
__global__ __launch_bounds__(256) void wt_kernel(const float* __restrict__ W,
                                                 short* __restrict__ WT) {
    const int c  = blockIdx.x >> 4;
    const int n0 = (blockIdx.x & 15) * 8;
    const int tid = threadIdx.x;
#pragma unroll
    for (int i = 0; i < 4; ++i) {
        int li = i * 256 + tid;
        int nn = li >> 7;
        int k  = li & 127;
        float v = W[(size_t)(c * 128 + k) * D128 + (n0 + nn)];
        WT[(size_t)c * (D128 * D128) + (size_t)(n0 + nn) * D128 + k] = f2bf(v);
    }
}

// Fused gather-GEMM, A-operand direct global->reg (no A staging):
// out[r] = bf16mfma( [x[src[r]] | x[dst[r]] | e[r]] @ W )
// Block: 512 threads = 8 waves arranged 4(row) x 2(col); wave tile 32x64.
__global__ __launch_bounds__(512, 4) void fused_kernel(
        const float* __restrict__ x,
        const float* __restrict__ e,
        const short* __restrict__ WT,
        const int*  __restrict__ src_idx,
        const int*  __restrict__ dst_idx,
        float* __restrict__ out)
{
    __shared__ short Ws[D128 * LDW];   // 34816 B, single B-chunk
    __shared__ int   ridx[2][TILE_M];

    const int tid = threadIdx.x;
    const int r0  = blockIdx.x * TILE_M;

    if (tid < TILE_M)            ridx[0][tid] = src_idx[r0 + tid];
    else if (tid < 2 * TILE_M)   ridx[1][tid - TILE_M] = dst_idx[r0 + tid - TILE_M];

    const int wave = tid >> 6;    // 0..7
    const int lane = tid & 63;
    const int wr   = wave >> 1;   // 0..3: which 32-row slab
    const int wc   = wave & 1;    // 0..1: which 64-col half
    const int lrow = lane & 15;
    const int lhi  = lane >> 4;   // 0..3

    f32x4 acc[2][4];
#pragma unroll
    for (int rg = 0; rg < 2; ++rg)
#pragma unroll
        for (int n = 0; n < 4; ++n)
            acc[rg][n] = (f32x4){0.f, 0.f, 0.f, 0.f};

    for (int c = 0; c < 3; ++c) {
        // ---- stage B chunk (32 KB bf16, L2-resident) ----
        __syncthreads();  // protect Ws from previous chunk's readers (also covers ridx at c=0)
        const short* Wc = WT + (size_t)c * (D128 * D128);
#pragma unroll
        for (int i = 0; i < 4; ++i) {
            int li = i * 512 + tid;      // 16B chunk id, 0..2047
            int n  = li >> 4;
            int k8 = li & 15;
            *reinterpret_cast<bf16x8*>(&Ws[n * LDW + k8 * 8]) =
                reinterpret_cast<const bf16x8*>(Wc)[li];
        }
        __syncthreads();

        // ---- per-wave row pointers for this chunk ----
        const float* rp[2];
#pragma unroll
        for (int rg = 0; rg < 2; ++rg) {
            int lr = wr * 32 + rg * 16 + lrow;
            rp[rg] = (c == 2) ? (e + (size_t)(r0 + lr) * D128)
                              : (x + (size_t)ridx[c][lr] * D128);
        }

        // ---- K=128 in 4 MFMA steps; A direct from global ----
#pragma unroll
        for (int ks = 0; ks < 4; ++ks) {
            bf16x8 a[2];
#pragma unroll
            for (int rg = 0; rg < 2; ++rg) {
                const float* p = rp[rg] + ks * 32 + lhi * 8;
                float4 v0 = reinterpret_cast<const float4*>(p)[0];
                float4 v1 = reinterpret_cast<const float4*>(p)[1];
                a[rg] = pack8(v0, v1);
            }
#pragma unroll
            for (int n = 0; n < 4; ++n) {
                bf16x8 b = *reinterpret_cast<const bf16x8*>(
                    &Ws[(wc * 64 + n * 16 + lrow) * LDW + ks * 32 + lhi * 8]);
#pragma unroll
                for (int rg = 0; rg < 2; ++rg)
                    acc[rg][n] = __builtin_amdgcn_mfma_f32_16x16x32_bf16(
                        a[rg], b, acc[rg][n], 0, 0, 0);
            }
        }
    }

    // ---- epilogue: C/D layout col=lane&15, row=(lane>>4)*4+reg ----
#pragma unroll
    for (int rg = 0; rg < 2; ++rg)
#pragma unroll
        for (int n = 0; n < 4; ++n)
#pragma unroll
            for (int j = 0; j < 4; ++j) {
                int row = r0 + wr * 32 + rg * 16 + lhi * 4 + j;
                int col = wc * 64 + n * 16 + lrow;
                out[(size_t)row * D128 + col] = acc[rg][n][j];
            }
}

extern "C" void kernel_launch(void* const* d_in, const int* in_sizes, int n_in,
                              void* d_out, int out_size, void* d_ws, size_t ws_size,
                              hipStream_t stream) {
    const float* x = (const float*)d_in[0];
    const float* e = (const float*)d_in[1];
    const float* W = (const float*)d_in[2];
    const int* src = (const int*)d_in[3];
    const int* dst = (const int*)d_in[4];
    float* out = (float*)d_out;
    short* WT  = (short*)d_ws;   // 3*128*128 bf16 = 96 KiB

    const int E = in_sizes[3];               // 400000
    const int blocks = E / TILE_M;           // 3125 (exact)

    wt_kernel<<<48, 256, 0, stream>>>(W, WT);
    fused_kernel<<<blocks, 512, 0, stream>>>(x, e, WT, src, dst, out);
}

// Round 3
// 136.914 us; speedup vs baseline: 1.4920x; 1.4368x over previous
//
#include <hip/hip_runtime.h>
#include <hip/hip_bf16.h>

typedef __attribute__((ext_vector_type(8))) short bf16x8;
typedef __attribute__((ext_vector_type(4))) float f32x4;

#define D128 128
#define TILE_M 128
#define LDW 136                  // shorts per padded Ws row
#define WCHUNK (D128 * LDW)      // 17408 shorts = 34816 B per chunk LDS image
#define XB_OFF (131072 / 2)      // xb starts at 128 KiB into d_ws (in shorts)

__device__ __forceinline__ short f2bf(float f) {
    union { float f; unsigned u; } v; v.f = f;
    unsigned r = (v.u + 0x7FFFu + ((v.u >> 16) & 1u)) >> 16;  // RNE
    return (short)r;
}

__device__ __forceinline__ short f2bf_h(float f) {
    __hip_bfloat16 h = __float2bfloat16(f);
    short s;
    __builtin_memcpy(&s, &h, sizeof(short));
    return s;
}

__device__ __forceinline__ bf16x8 pack8(float4 a, float4 b) {
    bf16x8 r;
    r[0] = f2bf_h(a.x); r[1] = f2bf_h(a.y); r[2] = f2bf_h(a.z); r[3] = f2bf_h(a.w);
    r[4] = f2bf_h(b.x); r[5] = f2bf_h(b.y); r[6] = f2bf_h(b.z); r[7] = f2bf_h(b.w);
    return r;
}

__device__ __forceinline__ void gload_lds16(const short* g, short* l) {
    __builtin_amdgcn_global_load_lds(
        (const __attribute__((address_space(1))) unsigned int*)(const void*)g,
        (__attribute__((address_space(3))) unsigned int*)(void*)l, 16, 0, 0);
}

// W (3*128 x 128 fp32 row-major) -> padded bf16 LDS image WTp[c][n*LDW + k].
__global__ __launch_bounds__(256) void wt_kernel(const float* __restrict__ W,
                                                 short* __restrict__ WTp) {
    const int c  = blockIdx.x >> 4;
    const int n0 = (blockIdx.x & 15) * 8;
    const int tid = threadIdx.x;
#pragma unroll
    for (int i = 0; i < 4; ++i) {
        int li = i * 256 + tid;          // 0..1023
        int nn = li >> 7;                // 0..7
        int k  = li & 127;
        float v = W[(size_t)(c * 128 + k) * D128 + (n0 + nn)];
        WTp[(size_t)c * WCHUNK + (size_t)(n0 + nn) * LDW + k] = f2bf(v);
    }
}

// x (fp32) -> xb (bf16), 8 elems/thread.
__global__ __launch_bounds__(256) void xb_kernel(const float* __restrict__ x,
                                                 short* __restrict__ xb) {
    const size_t i = ((size_t)blockIdx.x * 256 + threadIdx.x) * 8;
    float4 v0 = reinterpret_cast<const float4*>(x + i)[0];
    float4 v1 = reinterpret_cast<const float4*>(x + i)[1];
    *reinterpret_cast<bf16x8*>(xb + i) = pack8(v0, v1);
}

// Fused gather-GEMM, pipelined:
// out[r] = bf16mfma( [x[src[r]] | x[dst[r]] | e[r]] @ W )
// 512 threads = 8 waves; wave tile = 16 rows x 128 cols (no duplicate A loads).
__global__ __launch_bounds__(512, 4) void fused_kernel(
        const short* __restrict__ xb,
        const float* __restrict__ e,
        const short* __restrict__ WTp,
        const int*  __restrict__ src_idx,
        const int*  __restrict__ dst_idx,
        float* __restrict__ out)
{
    __shared__ short Ws[2][WCHUNK];   // 2 x 34816 B

    const int tid  = threadIdx.x;
    const int r0   = blockIdx.x * TILE_M;
    const int w    = tid >> 6;
    const int lane = tid & 63;
    const int lrow = lane & 15;
    const int lhi  = lane >> 4;       // 0..3
    const int arow = w * 16 + lrow;   // the gathered row this lane loads

    const int si = src_idx[r0 + arow];
    const int di = dst_idx[r0 + arow];
    const short* xrow_s = xb + (size_t)si * D128;
    const short* xrow_d = xb + (size_t)di * D128;
    const float* erow   = e + (size_t)(r0 + arow) * D128;

    f32x4 acc[8];
#pragma unroll
    for (int n = 0; n < 8; ++n) acc[n] = (f32x4){0.f, 0.f, 0.f, 0.f};

    // ---- helpers ----
    auto stageB = [&](short* dstbuf, const short* srcw) {
        const int base = w * 64;                     // 16B-unit base for this wave
#pragma unroll
        for (int j = 0; j < 4; ++j) {
            int unit = j * 512 + base;
            gload_lds16(srcw + (size_t)(unit + lane) * 8, dstbuf + (size_t)unit * 8);
        }
        if (w < 2) {                                  // ragged tail: 2176 units total
            int unit = 2048 + base;
            gload_lds16(srcw + (size_t)(unit + lane) * 8, dstbuf + (size_t)unit * 8);
        }
    };
    auto loadA_x = [&](bf16x8 a[4], const short* rowp) {
#pragma unroll
        for (int ks = 0; ks < 4; ++ks)
            a[ks] = *reinterpret_cast<const bf16x8*>(rowp + ks * 32 + lhi * 8);
    };
    auto mfma_phase = [&](const bf16x8 a[4], const short* Wbuf) {
#pragma unroll
        for (int ks = 0; ks < 4; ++ks)
#pragma unroll
            for (int n = 0; n < 8; ++n) {
                bf16x8 b = *reinterpret_cast<const bf16x8*>(
                    &Wbuf[(n * 16 + lrow) * LDW + ks * 32 + lhi * 8]);
                acc[n] = __builtin_amdgcn_mfma_f32_16x16x32_bf16(a[ks], b, acc[n], 0, 0, 0);
            }
    };

    // ---- prologue: stage B0, load A0 (src) ----
    stageB(Ws[0], WTp);
    asm volatile("" ::: "memory");        // pin: stage issued before A0 loads
    bf16x8 a_cur[4];
    loadA_x(a_cur, xrow_s);
    asm volatile("s_waitcnt vmcnt(4)" ::: "memory");   // B0 staged; A0 may fly
    __builtin_amdgcn_s_barrier();

    // ---- iter c=0: compute src chunk, prefetch B1 + A1 (dst) ----
    stageB(Ws[1], WTp + WCHUNK);
    asm volatile("" ::: "memory");
    bf16x8 a_nxt[4];
    loadA_x(a_nxt, xrow_d);
    mfma_phase(a_cur, Ws[0]);
    asm volatile("s_waitcnt vmcnt(4)" ::: "memory");   // B1 staged; A1 may fly
    __builtin_amdgcn_s_barrier();

    // ---- iter c=1: compute dst chunk, prefetch B2 (into buf0) + e rows ----
    stageB(Ws[0], WTp + 2 * WCHUNK);
    asm volatile("" ::: "memory");
    float4 ev[8];
#pragma unroll
    for (int ks = 0; ks < 4; ++ks) {
        ev[2 * ks]     = reinterpret_cast<const float4*>(erow + ks * 32 + lhi * 8)[0];
        ev[2 * ks + 1] = reinterpret_cast<const float4*>(erow + ks * 32 + lhi * 8)[1];
    }
    mfma_phase(a_nxt, Ws[1]);
    asm volatile("s_waitcnt vmcnt(8)" ::: "memory");   // B2 staged; e loads may fly
    __builtin_amdgcn_s_barrier();

    // ---- iter c=2: convert e, compute e chunk ----
    bf16x8 a_e[4];
#pragma unroll
    for (int ks = 0; ks < 4; ++ks) a_e[ks] = pack8(ev[2 * ks], ev[2 * ks + 1]);
    mfma_phase(a_e, Ws[0]);

    // ---- epilogue: C/D layout col=lane&15, row=(lane>>4)*4+reg ----
#pragma unroll
    for (int n = 0; n < 8; ++n)
#pragma unroll
        for (int j = 0; j < 4; ++j) {
            int row = r0 + w * 16 + lhi * 4 + j;
            int col = n * 16 + lrow;
            out[(size_t)row * D128 + col] = acc[n][j];
        }
}

extern "C" void kernel_launch(void* const* d_in, const int* in_sizes, int n_in,
                              void* d_out, int out_size, void* d_ws, size_t ws_size,
                              hipStream_t stream) {
    const float* x = (const float*)d_in[0];
    const float* e = (const float*)d_in[1];
    const float* W = (const float*)d_in[2];
    const int* src = (const int*)d_in[3];
    const int* dst = (const int*)d_in[4];
    float* out = (float*)d_out;

    short* WTp = (short*)d_ws;                  // 3 * 34816 B padded W images
    short* xb  = (short*)d_ws + XB_OFF;         // 100000*128 bf16 = 25.6 MB

    const int N = in_sizes[0] / D128;           // 100000
    const int E = in_sizes[3];                  // 400000
    const int blocks = E / TILE_M;              // 3125 (exact)

    wt_kernel<<<48, 256, 0, stream>>>(W, WTp);
    xb_kernel<<<(N * D128) / (256 * 8), 256, 0, stream>>>(x, xb);
    fused_kernel<<<blocks, 512, 0, stream>>>(xb, e, WTp, src, dst, out);
}